// Round 16
// baseline (33857.367 us; speedup 1.0000x reference)
//
#include <hip/hip_runtime.h>
#include <hip/hip_bf16.h>

// LSTM: B=128, T=1024, D=H=768.
// R16: (1) chunked pipelined h-staging (3x8 loads, ta/tb ping-pong, 64 regs)
// to fix R12/R15's VGPR=256 cap (R9 best ran at 204); (2) R6-style bisect:
// flowA (no wait), flowB (no wait/no stage), flowC (no wait/no X) at T=256
// as separate rocprof rows to locate the 24us/step eater if the fix misses.
// Memory design (proven R15): Whh pinned LDS, 192 WGs x 128thr, h staged to
// LDS via device-scope loads, nt out-stores, single final[t] counter.

typedef __attribute__((ext_vector_type(8))) short short8v;   // 8 bf16 = 4 VGPR
typedef __attribute__((ext_vector_type(16))) float f32x16;   // 32x32 acc
typedef __attribute__((ext_vector_type(4))) float f32x4;     // native vec nt-store

constexpr int B_ = 128, T_ = 1024, D_ = 768, H_ = 768;
constexpr int NWG = 192;                               // 48 jq x 4 batch-blocks

constexpr size_t FINAL_U32 = 1025ull * 16;             // final[t][16] u32
constexpr size_t PING_OFF  = 66048;                    // 512-aligned
constexpr size_t HSLOT_SH  = 96ull * 128 * 8;          // 98304 shorts = 196608 B
constexpr size_t BIAS_OFF  = PING_OFF + 393216;        // 459264
constexpr size_t WHH_OFF   = BIAS_OFF + 12288;         // 471552
constexpr size_t WIH_OFF   = WHH_OFF + 4718592;        // 5190144
constexpr size_t XT_OFF    = WIH_OFF + 4718592;        // 9908736
constexpr size_t WS_NEED   = XT_OFF + 201326592;       // 211235328

__device__ __forceinline__ unsigned short f2bf(float f) {
  union { float f; unsigned u; } v; v.f = f;
  unsigned r = v.u + 0x7FFF + ((v.u >> 16) & 1);       // RNE
  return (unsigned short)(r >> 16);
}
__device__ __forceinline__ float sigmf(float x) { return 1.0f / (1.0f + __expf(-x)); }
__device__ __forceinline__ float tanhf_(float x) {
  float ax = fabsf(x);
  float e = __expf(-2.0f * ax);
  float t = (1.0f - e) / (1.0f + e);
  return copysignf(t, x);
}

// ---------------- P1: x -> xTb[t][kb][b][ko] bf16 ------------------------
__global__ void k_xT(const float* __restrict__ x, unsigned short* __restrict__ xTb) {
  __shared__ float tile[16][776];
  const int t = blockIdx.x;
  const int tid = threadIdx.x;
  for (int chunk = 0; chunk < 8; ++chunk) {
    #pragma unroll
    for (int i = 0; i < 12; ++i) {
      int id = i * 256 + tid;
      int bl = id / 192, d4 = id % 192;
      int b = chunk * 16 + bl;
      float4 v = *(const float4*)(x + ((size_t)b * T_ + t) * D_ + d4 * 4);
      *(float4*)&tile[bl][d4 * 4] = v;
    }
    __syncthreads();
    #pragma unroll
    for (int i = 0; i < 6; ++i) {
      int id = i * 256 + tid;
      int kb = id >> 4, bl = id & 15;
      int b = chunk * 16 + bl;
      const float* src = &tile[bl][kb * 8];
      unsigned short tmp[8];
      #pragma unroll
      for (int k = 0; k < 8; ++k) tmp[k] = f2bf(src[k]);
      *(short8v*)(xTb + (((size_t)t * 96 + kb) * 128 + b) * 8) = *(short8v*)tmp;
    }
    __syncthreads();
  }
}

// ---------------- P2: weight images --------------------------------------
__global__ void k_prep_w(const float* __restrict__ whh, const float* __restrict__ wih,
                         unsigned short* __restrict__ Whh_img,
                         unsigned short* __restrict__ Wih_img) {
  int id  = blockIdx.x * 256 + threadIdx.x;            // exactly 589824
  int img = id / 294912;
  int rem = id - img * 294912;
  int s   = rem / 3072;
  int rem2 = rem - s * 3072;
  int kc  = rem2 >> 5;
  int col = rem2 & 31;
  int grow = (col >> 3) * H_ + s * 8 + (col & 7);
  const float* W = img ? wih : whh;
  const float* p = W + (size_t)grow * D_ + kc * 8;
  float4 v0 = *(const float4*)p;
  float4 v1 = *(const float4*)(p + 4);
  unsigned short o[8] = {f2bf(v0.x), f2bf(v0.y), f2bf(v0.z), f2bf(v0.w),
                         f2bf(v1.x), f2bf(v1.y), f2bf(v1.z), f2bf(v1.w)};
  unsigned short* dst = (img ? Wih_img : Whh_img) + (size_t)rem * 8;
  *(short8v*)dst = *(short8v*)o;
}

// ---------------- P3: bias_img, h0 -> ping slot0, zero final -------------
__global__ void k_prep_s(const float* __restrict__ h0,
                         const float* __restrict__ bih, const float* __restrict__ bhh,
                         unsigned short* __restrict__ hping,
                         float* __restrict__ bias_img,
                         unsigned* __restrict__ finalc) {
  int id = blockIdx.x * 256 + threadIdx.x;             // exactly 98304
  int b = id / 768, j = id - b * 768;
  hping[(size_t)(j >> 3) * 1024 + b * 8 + (j & 7)] = f2bf(h0[id]);
  if (id < 3072) {
    int s = id >> 5, col = id & 31;
    int grow = (col >> 3) * H_ + s * 8 + (col & 7);
    bias_img[id] = bih[grow] + bhh[grow];
  }
  if (id < (int)FINAL_U32) finalc[id] = 0;
}

// ---------------- main recurrent body ------------------------------------
// MODE bits: 1=WAIT, 2=STAGE, 4=XPHASE.  TS = steps.
template <int MODE, int TS>
__device__ __forceinline__ void lstm_body(
    const unsigned short* __restrict__ xTb,
    const unsigned short* __restrict__ Whh_img,
    const unsigned short* __restrict__ Wih_img,
    const float* __restrict__ bias_img,
    const float* __restrict__ c0,
    unsigned short* __restrict__ hping, unsigned* finalc,
    float* __restrict__ out, float* __restrict__ hT, float* __restrict__ cT) {
  constexpr bool WAIT = MODE & 1, STAGE = MODE & 2, XPH = MODE & 4;
  __shared__ __align__(16) unsigned short Whh_l[2 * 96 * 32 * 8];  // 96 KB
  __shared__ __align__(16) unsigned short hbuf[96 * 32 * 8];       // 48 KB

  const int wj   = blockIdx.x;        // = jq*4 + c
  const int jq   = wj >> 2;
  const int c    = wj & 3;
  const int tid  = threadIdx.x;
  const int w    = tid >> 6;
  const int lane = tid & 63;
  const int col  = lane & 31;
  const int kh   = lane >> 5;
  const int s    = jq * 2 + w;

  const int bg = 32 * c + col;
  const int jg = s * 8 + 4 * kh;

  { // stage Whh slices once
    const short8v* src = (const short8v*)(Whh_img + (size_t)(jq * 2) * 24576);
    short8v* dst = (short8v*)Whh_l;
    for (int i = tid; i < 6144; i += 128) dst[i] = src[i];
  }
  __syncthreads();

  const unsigned short* wih_base = Wih_img + (size_t)s * 24576;

  float bias_r[16];
  #pragma unroll
  for (int q = 0; q < 16; ++q)
    bias_r[q] = bias_img[s * 32 + (q & 3) + 8 * (q >> 2) + 4 * kh];

  float c_r[4];
  {
    float4 v = *(const float4*)(c0 + (size_t)bg * H_ + jg);
    c_r[0] = v.x; c_r[1] = v.y; c_r[2] = v.z; c_r[3] = v.w;
  }

  f32x16 accs[4];
  { // phase X for t=0
    #pragma unroll
    for (int q = 0; q < 16; ++q) {
      accs[0][q] = bias_r[q]; accs[1][q] = 0.f; accs[2][q] = 0.f; accs[3][q] = 0.f;
    }
    if constexpr (XPH) {
      #pragma unroll
      for (int f = 0; f < 48; ++f) {
        int kc = 2 * f + kh;
        short8v wv = *(const short8v*)(wih_base + (kc * 32 + col) * 8);
        short8v xv = *(const short8v*)(xTb + ((size_t)kc * 128 + bg) * 8);
        accs[f & 3] = __builtin_amdgcn_mfma_f32_32x32x16_bf16(wv, xv, accs[f & 3], 0, 0, 0);
      }
    }
  }

  for (int t = 0; t < TS; ++t) {
    if (t > 0) {
      if (WAIT && w == 0) {
        const unsigned* fp = finalc + (size_t)t * 16;
        for (;;) {
          unsigned v = __hip_atomic_load(fp, __ATOMIC_RELAXED, __HIP_MEMORY_SCOPE_AGENT);
          if (v >= (unsigned)NWG) break;
          __builtin_amdgcn_s_sleep(4);
        }
      }
      __syncthreads();
      asm volatile("" ::: "memory");
    }

    // stage h (48KB) -> LDS: 3 pipelined chunks of 8 (64 staging regs max)
    if constexpr (STAGE) {
      const unsigned short* hb_rd = hping + (size_t)(t & 1) * HSLOT_SH;
      short8v ta[8], tb[8];
      #pragma unroll
      for (int i = 0; i < 8; ++i) {          // chunk0 -> ta
        int id = i * 128 + tid;
        int kb = id >> 5, bp = id & 31;
        asm volatile("global_load_dwordx4 %0, %1, off sc0 sc1"
                     : "=v"(ta[i]) : "v"(hb_rd + ((size_t)kb * 128 + 32 * c + bp) * 8));
      }
      #pragma unroll
      for (int i = 0; i < 8; ++i) {          // chunk1 -> tb
        int id = (i + 8) * 128 + tid;
        int kb = id >> 5, bp = id & 31;
        asm volatile("global_load_dwordx4 %0, %1, off sc0 sc1"
                     : "=v"(tb[i]) : "v"(hb_rd + ((size_t)kb * 128 + 32 * c + bp) * 8));
      }
      asm volatile("s_waitcnt vmcnt(8)" ::: "memory");   // chunk0 done (FIFO)
      __builtin_amdgcn_sched_barrier(0);
      #pragma unroll
      for (int i = 0; i < 8; ++i)
        *(short8v*)&hbuf[(size_t)(i * 128 + tid) * 8] = ta[i];
      #pragma unroll
      for (int i = 0; i < 8; ++i) {          // chunk2 -> ta (reuse)
        int id = (i + 16) * 128 + tid;
        int kb = id >> 5, bp = id & 31;
        asm volatile("global_load_dwordx4 %0, %1, off sc0 sc1"
                     : "=v"(ta[i]) : "v"(hb_rd + ((size_t)kb * 128 + 32 * c + bp) * 8));
      }
      asm volatile("s_waitcnt vmcnt(8)" ::: "memory");   // chunk1 done
      __builtin_amdgcn_sched_barrier(0);
      #pragma unroll
      for (int i = 0; i < 8; ++i)
        *(short8v*)&hbuf[(size_t)((i + 8) * 128 + tid) * 8] = tb[i];
      asm volatile("s_waitcnt vmcnt(0)" ::: "memory");   // chunk2 done
      __builtin_amdgcn_sched_barrier(0);
      #pragma unroll
      for (int i = 0; i < 8; ++i)
        *(short8v*)&hbuf[(size_t)((i + 16) * 128 + tid) * 8] = ta[i];
    }
    __syncthreads();

    // phase H: A=W_hh (LDS), B=h (LDS)
    #pragma unroll
    for (int f = 0; f < 48; ++f) {
      int kc = 2 * f + kh;
      short8v wv = *(const short8v*)&Whh_l[((w * 96 + kc) * 32 + col) * 8];
      short8v hB = *(const short8v*)&hbuf[(kc * 32 + col) * 8];
      accs[f & 3] = __builtin_amdgcn_mfma_f32_32x32x16_bf16(wv, hB, accs[f & 3], 0, 0, 0);
    }

    f32x16 g;
    #pragma unroll
    for (int q = 0; q < 16; ++q)
      g[q] = (accs[0][q] + accs[1][q]) + (accs[2][q] + accs[3][q]);

    float hnew[4];
    #pragma unroll
    for (int m = 0; m < 4; ++m) {
      float gi = g[m];
      float gf = g[4 + m];
      float gg = g[8 + m];
      float go = g[12 + m];
      float cn = sigmf(gf) * c_r[m] + sigmf(gi) * tanhf_(gg);
      c_r[m] = cn;
      hnew[m] = sigmf(go) * tanhf_(cn);
    }

    // h exchange: 8B sc1 write-through
    union { ushort4 sv; unsigned long long u; } hv;
    hv.sv = (ushort4){f2bf(hnew[0]), f2bf(hnew[1]), f2bf(hnew[2]), f2bf(hnew[3])};
    __hip_atomic_store(
        (unsigned long long*)(hping + (size_t)((t + 1) & 1) * HSLOT_SH +
                              ((size_t)s * 128 + bg) * 8 + 4 * kh),
        hv.u, __ATOMIC_RELAXED, __HIP_MEMORY_SCOPE_AGENT);

    // release
    asm volatile("s_waitcnt vmcnt(0)" ::: "memory");
    __syncthreads();
    if (tid == 0)
      __hip_atomic_fetch_add(finalc + (size_t)(t + 1) * 16, 1u,
                             __ATOMIC_RELAXED, __HIP_MEMORY_SCOPE_AGENT);

    // out stores (non-temporal) after release
    f32x4 ov = {hnew[0], hnew[1], hnew[2], hnew[3]};
    __builtin_nontemporal_store(ov, (f32x4*)(out + ((size_t)bg * T_ + t) * H_ + jg));
    if (t == TS - 1) {
      *(f32x4*)(hT + (size_t)bg * H_ + jg) = ov;
      f32x4 cv = {c_r[0], c_r[1], c_r[2], c_r[3]};
      *(f32x4*)(cT + (size_t)bg * H_ + jg) = cv;
    }

    // phase X for t+1
    if (t + 1 < TS) {
      #pragma unroll
      for (int q = 0; q < 16; ++q) {
        accs[0][q] = bias_r[q]; accs[1][q] = 0.f; accs[2][q] = 0.f; accs[3][q] = 0.f;
      }
      if constexpr (XPH) {
        const unsigned short* xp = xTb + (size_t)(t + 1) * 96 * 128 * 8;
        #pragma unroll
        for (int f = 0; f < 48; ++f) {
          int kc = 2 * f + kh;
          short8v wv = *(const short8v*)(wih_base + (kc * 32 + col) * 8);
          short8v xv = *(const short8v*)(xp + ((size_t)kc * 128 + bg) * 8);
          accs[f & 3] = __builtin_amdgcn_mfma_f32_32x32x16_bf16(wv, xv, accs[f & 3], 0, 0, 0);
        }
      }
    }
  }
}

__launch_bounds__(128, 1)
__global__ void k_lstm(const unsigned short* __restrict__ xTb,
                       const unsigned short* __restrict__ Whh_img,
                       const unsigned short* __restrict__ Wih_img,
                       const float* __restrict__ bias_img,
                       const float* __restrict__ c0,
                       unsigned short* __restrict__ hping, unsigned* finalc,
                       float* __restrict__ out, float* __restrict__ hT,
                       float* __restrict__ cT) {
  lstm_body<7, 1024>(xTb, Whh_img, Wih_img, bias_img, c0, hping, finalc, out, hT, cT);
}
__launch_bounds__(128, 1)
__global__ void k_flowA(const unsigned short* __restrict__ xTb,
                        const unsigned short* __restrict__ Whh_img,
                        const unsigned short* __restrict__ Wih_img,
                        const float* __restrict__ bias_img,
                        const float* __restrict__ c0,
                        unsigned short* __restrict__ hping, unsigned* finalc,
                        float* __restrict__ out, float* __restrict__ hT,
                        float* __restrict__ cT) {
  lstm_body<6, 256>(xTb, Whh_img, Wih_img, bias_img, c0, hping, finalc, out, hT, cT);
}
__launch_bounds__(128, 1)
__global__ void k_flowB(const unsigned short* __restrict__ xTb,
                        const unsigned short* __restrict__ Whh_img,
                        const unsigned short* __restrict__ Wih_img,
                        const float* __restrict__ bias_img,
                        const float* __restrict__ c0,
                        unsigned short* __restrict__ hping, unsigned* finalc,
                        float* __restrict__ out, float* __restrict__ hT,
                        float* __restrict__ cT) {
  lstm_body<4, 256>(xTb, Whh_img, Wih_img, bias_img, c0, hping, finalc, out, hT, cT);
}
__launch_bounds__(128, 1)
__global__ void k_flowC(const unsigned short* __restrict__ xTb,
                        const unsigned short* __restrict__ Whh_img,
                        const unsigned short* __restrict__ Wih_img,
                        const float* __restrict__ bias_img,
                        const float* __restrict__ c0,
                        unsigned short* __restrict__ hping, unsigned* finalc,
                        float* __restrict__ out, float* __restrict__ hT,
                        float* __restrict__ cT) {
  lstm_body<2, 256>(xTb, Whh_img, Wih_img, bias_img, c0, hping, finalc, out, hT, cT);
}

extern "C" void kernel_launch(void* const* d_in, const int* in_sizes, int n_in,
                              void* d_out, int out_size, void* d_ws, size_t ws_size,
                              hipStream_t stream) {
  const float* x   = (const float*)d_in[0];
  const float* h0  = (const float*)d_in[1];
  const float* c0  = (const float*)d_in[2];
  const float* wih = (const float*)d_in[3];
  const float* whh = (const float*)d_in[4];
  const float* bih = (const float*)d_in[5];
  const float* bhh = (const float*)d_in[6];

  float* out = (float*)d_out;
  float* hT  = out + (size_t)B_ * T_ * H_;
  float* cT  = hT + (size_t)B_ * H_;

  if (ws_size < WS_NEED) return;

  char* ws = (char*)d_ws;
  unsigned*       finalc = (unsigned*)(ws);
  unsigned short* hping  = (unsigned short*)(ws + PING_OFF);
  float*          biasc  = (float*)(ws + BIAS_OFF);
  unsigned short* WhhI   = (unsigned short*)(ws + WHH_OFF);
  unsigned short* WihI   = (unsigned short*)(ws + WIH_OFF);
  unsigned short* xTp    = (unsigned short*)(ws + XT_OFF);

  k_xT<<<dim3(T_), dim3(256), 0, stream>>>(x, xTp);
  k_prep_w<<<dim3(589824 / 256), dim3(256), 0, stream>>>(whh, wih, WhhI, WihI);
  k_prep_s<<<dim3((B_ * H_) / 256), dim3(256), 0, stream>>>(h0, bih, bhh, hping, biasc, finalc);

  // diagnostics (T=256, no waits; state re-prepped before the real run)
  k_flowA<<<dim3(NWG), dim3(128), 0, stream>>>(xTp, WhhI, WihI, biasc, c0, hping, finalc, out, hT, cT);
  k_flowB<<<dim3(NWG), dim3(128), 0, stream>>>(xTp, WhhI, WihI, biasc, c0, hping, finalc, out, hT, cT);
  k_flowC<<<dim3(NWG), dim3(128), 0, stream>>>(xTp, WhhI, WihI, biasc, c0, hping, finalc, out, hT, cT);

  k_prep_s<<<dim3((B_ * H_) / 256), dim3(256), 0, stream>>>(h0, bih, bhh, hping, biasc, finalc);
  k_lstm<<<dim3(NWG), dim3(128), 0, stream>>>(xTp, WhhI, WihI, biasc, c0, hping, finalc, out, hT, cT);
}

// Round 17
// 9234.734 us; speedup vs baseline: 3.6663x; 3.6663x over previous
//
#include <hip/hip_runtime.h>
#include <hip/hip_bf16.h>

// LSTM: B=128, T=1024, D=H=768.
// R17: the R9 structure (best: 10.9ms; W in LDS, per-wave direct sc1 h-loads,
// no LDS h-staging) split 2x: 192 WGs x 128 thr. Each R9 WG (j-group, 128
// batch) becomes two WGs (same j-group, 64 batch each). Per-CU h bytes halve
// (192KB -> 96KB/step); per-XCD request totals unchanged. Clean A/B:
// per-CU-return-bound -> ~6.5ms; per-XCD-rate-bound -> ~11ms.
// Staged-LDS family (R12/15/16, 22-25ms) abandoned: 2-wave serial chains
// expose every latency. Sync: single final[t] counter, threshold 192. Out
// stores non-temporal. Everything else verbatim R9.

typedef __attribute__((ext_vector_type(8))) short short8v;   // 8 bf16 = 4 VGPR
typedef __attribute__((ext_vector_type(16))) float f32x16;   // 32x32 acc
typedef __attribute__((ext_vector_type(4))) float f32x4;     // native vec nt-store

constexpr int B_ = 128, T_ = 1024, D_ = 768, H_ = 768;
constexpr int NWG = 192;         // 96 j-groups x 2 batch halves

constexpr size_t FINAL_U32 = 1025ull * 16;             // final[t][16] u32
constexpr size_t PING_OFF  = 66048;                    // 512-aligned
constexpr size_t HSLOT_SH  = 96ull * 128 * 8;          // 98304 shorts = 196608 B
constexpr size_t BIAS_OFF  = PING_OFF + 393216;        // 459264
constexpr size_t WC_OFF    = BIAS_OFF + 12288;         // 471552 (9437184 B)
constexpr size_t XT_OFF    = WC_OFF + 9437184;         // 9908736
constexpr size_t WS_NEED   = XT_OFF + 201326592;       // 211235328 (known-good)

__device__ __forceinline__ unsigned short f2bf(float f) {
  union { float f; unsigned u; } v; v.f = f;
  unsigned r = v.u + 0x7FFF + ((v.u >> 16) & 1);       // RNE
  return (unsigned short)(r >> 16);
}
__device__ __forceinline__ float sigmf(float x) { return 1.0f / (1.0f + __expf(-x)); }
__device__ __forceinline__ float tanhf_(float x) {
  float ax = fabsf(x);
  float e = __expf(-2.0f * ax);
  float t = (1.0f - e) / (1.0f + e);
  return copysignf(t, x);
}

// ---------------- P1: x -> xTb[t][kb][b][ko] bf16 ------------------------
__global__ void k_xT(const float* __restrict__ x, unsigned short* __restrict__ xTb) {
  __shared__ float tile[16][776];
  const int t = blockIdx.x;
  const int tid = threadIdx.x;
  for (int chunk = 0; chunk < 8; ++chunk) {
    #pragma unroll
    for (int i = 0; i < 12; ++i) {
      int id = i * 256 + tid;
      int bl = id / 192, d4 = id % 192;
      int b = chunk * 16 + bl;
      float4 v = *(const float4*)(x + ((size_t)b * T_ + t) * D_ + d4 * 4);
      *(float4*)&tile[bl][d4 * 4] = v;
    }
    __syncthreads();
    #pragma unroll
    for (int i = 0; i < 6; ++i) {
      int id = i * 256 + tid;
      int kb = id >> 4, bl = id & 15;
      int b = chunk * 16 + bl;
      const float* src = &tile[bl][kb * 8];
      unsigned short tmp[8];
      #pragma unroll
      for (int k = 0; k < 8; ++k) tmp[k] = f2bf(src[k]);
      *(short8v*)(xTb + (((size_t)t * 96 + kb) * 128 + b) * 8) = *(short8v*)tmp;
    }
    __syncthreads();
  }
}

// ---------------- P2: weight slices, swizzled (R9 image) -----------------
// Wc chunk id = jg*6144 + src*3072 + r*96 + kcp ; chunk = 8 bf16 (16B)
// LDS image per j-group: [src(2)][r(32)][kc'(96)] ; kc' = kc ^ (r&15)
__global__ void k_prep_w(const float* __restrict__ wih, const float* __restrict__ whh,
                         unsigned short* __restrict__ Wc) {
  int id  = blockIdx.x * 256 + threadIdx.x;            // exactly 589824
  int jg  = id / 6144;
  int rem = id - jg * 6144;
  int src = rem / 3072; rem -= src * 3072;
  int r   = rem / 96;
  int kcp = rem - r * 96;
  int kc  = kcp ^ (r & 15);
  int grow = (r >> 3) * H_ + jg * 8 + (r & 7);         // gate*768 + j
  const float* W = (src == 0) ? whh : wih;
  const float* p = W + (size_t)grow * D_ + kc * 8;
  float4 v0 = *(const float4*)p;
  float4 v1 = *(const float4*)(p + 4);
  ushort4 o0 = {f2bf(v0.x), f2bf(v0.y), f2bf(v0.z), f2bf(v0.w)};
  ushort4 o1 = {f2bf(v1.x), f2bf(v1.y), f2bf(v1.z), f2bf(v1.w)};
  *(ushort4*)(Wc + (size_t)id * 8)     = o0;
  *(ushort4*)(Wc + (size_t)id * 8 + 4) = o1;
}

// ---------------- P3: bias, h0 -> ping slot0, zero final -----------------
__global__ void k_prep_s(const float* __restrict__ h0,
                         const float* __restrict__ bih, const float* __restrict__ bhh,
                         unsigned short* __restrict__ hping,
                         float* __restrict__ bias_c,
                         unsigned* __restrict__ finalc) {
  int id = blockIdx.x * 256 + threadIdx.x;             // exactly 98304
  int b = id / 768, j = id - b * 768;
  hping[(size_t)(j >> 3) * 1024 + b * 8 + (j & 7)] = f2bf(h0[id]);
  if (id < 3072) {
    int jg = id >> 5, r = id & 31;
    int grow = (r >> 3) * H_ + jg * 8 + (r & 7);
    bias_c[id] = bih[grow] + bhh[grow];
  }
  if (id < (int)FINAL_U32) finalc[id] = 0;
}

// ---------------- main recurrent kernel ----------------------------------
__launch_bounds__(128, 1)
__global__ void k_lstm(const unsigned short* __restrict__ xTb,
                       const unsigned short* __restrict__ Wc,
                       const float* __restrict__ bias_c,
                       const float* __restrict__ c0,
                       unsigned short* __restrict__ hping, // [2][96][128][8] bf16
                       unsigned* finalc,                   // [1025][16]
                       float* __restrict__ out,
                       float* __restrict__ hT,
                       float* __restrict__ cT) {
  __shared__ __align__(16) unsigned short Wl[2 * 32 * 768];   // 96 KB (Whh|Wih)
  __shared__ float bias_l[32];

  const int wj   = blockIdx.x;        // = jgroup*2 + half
  const int jgrp = wj >> 1;           // j-group [0,96)
  const int half = wj & 1;            // batch half: bands 2*half, 2*half+1
  const int tid  = threadIdx.x;
  const int wave = tid >> 6;          // band-in-half
  const int lane = tid & 63;
  const int col  = lane & 31;
  const int kh   = lane >> 5;
  const int sw   = col & 15;

  { // stage weight slices (pre-swizzled) once: 6144 x 16B by 128 threads
    const short8v* s = (const short8v*)(Wc + (size_t)jgrp * 49152);
    short8v* d = (short8v*)Wl;
    for (int i = tid; i < 6144; i += 128) d[i] = s[i];
    if (tid < 32) bias_l[tid] = bias_c[jgrp * 32 + tid];
  }
  __syncthreads();

  const int bg = (half * 2 + wave) * 32 + col;   // global batch row
  const int jg = jgrp * 8 + 4 * kh;              // global h col base

  float c_r[4];
  {
    float4 v = *(const float4*)(c0 + (size_t)bg * H_ + jg);
    c_r[0] = v.x; c_r[1] = v.y; c_r[2] = v.z; c_r[3] = v.w;
  }

  const char* wlb = (const char*)Wl;
  const int wrow0 = col * 1536;             // W_hh A-row base (bytes)
  const int wrow1 = 49152 + col * 1536;     // W_ih A-row base

  float bias_r[16];
  #pragma unroll
  for (int q = 0; q < 16; ++q) bias_r[q] = bias_l[(q & 3) + 8 * (q >> 2) + 4 * kh];

  f32x16 accs[4];
  { // phase X for t=0
    #pragma unroll
    for (int q = 0; q < 16; ++q) {
      accs[0][q] = bias_r[q]; accs[1][q] = 0.f; accs[2][q] = 0.f; accs[3][q] = 0.f;
    }
    const unsigned short* xp = xTb + (size_t)kh * 1024 + bg * 8;
    #pragma unroll
    for (int f = 0; f < 48; ++f) {
      short8v w = *(const short8v*)(wlb + wrow1 + (((2 * f + kh) ^ sw) << 4));
      short8v xv = *(const short8v*)(xp + f * 2048);
      accs[f & 3] = __builtin_amdgcn_mfma_f32_32x32x16_bf16(w, xv, accs[f & 3], 0, 0, 0);
    }
  }

  for (int t = 0; t < T_; ++t) {
    if (t > 0) {
      if (wave == 0) {
        const unsigned* fp = finalc + (size_t)t * 16;
        for (;;) {
          unsigned v = __hip_atomic_load(fp, __ATOMIC_RELAXED, __HIP_MEMORY_SCOPE_AGENT);
          if (v >= (unsigned)NWG) break;
          __builtin_amdgcn_s_sleep(4);
        }
      }
      __syncthreads();
      asm volatile("" ::: "memory");
    }

    // phase H: 48 coalesced sc1 16B loads direct to regs, split-drain MFMA
    short8v hfrag[48];
    {
      const unsigned short* hp =
          hping + (size_t)(t & 1) * HSLOT_SH + (size_t)kh * 1024 + bg * 8;
      #pragma unroll
      for (int f = 0; f < 48; ++f) {
        asm volatile("global_load_dwordx4 %0, %1, off sc0 sc1"
                     : "=v"(hfrag[f]) : "v"(hp + f * 2048));
      }
    }
    asm volatile("s_waitcnt vmcnt(24)" ::: "memory");
    __builtin_amdgcn_sched_barrier(0);
    #pragma unroll
    for (int f = 0; f < 24; ++f) {
      short8v w = *(const short8v*)(wlb + wrow0 + (((2 * f + kh) ^ sw) << 4));
      accs[f & 3] = __builtin_amdgcn_mfma_f32_32x32x16_bf16(w, hfrag[f], accs[f & 3], 0, 0, 0);
    }
    asm volatile("s_waitcnt vmcnt(0)" ::: "memory");
    __builtin_amdgcn_sched_barrier(0);
    #pragma unroll
    for (int f = 24; f < 48; ++f) {
      short8v w = *(const short8v*)(wlb + wrow0 + (((2 * f + kh) ^ sw) << 4));
      accs[f & 3] = __builtin_amdgcn_mfma_f32_32x32x16_bf16(w, hfrag[f], accs[f & 3], 0, 0, 0);
    }

    f32x16 g;
    #pragma unroll
    for (int q = 0; q < 16; ++q)
      g[q] = (accs[0][q] + accs[1][q]) + (accs[2][q] + accs[3][q]);

    float hnew[4];
    #pragma unroll
    for (int m = 0; m < 4; ++m) {
      float gi = g[m];
      float gf = g[4 + m];
      float gg = g[8 + m];
      float go = g[12 + m];
      float cn = sigmf(gf) * c_r[m] + sigmf(gi) * tanhf_(gg);
      c_r[m] = cn;
      hnew[m] = sigmf(go) * tanhf_(cn);
    }

    // h exchange: coalesced 8B sc1 write-through (kb = jgrp)
    union { ushort4 sv; unsigned long long u; } hv;
    hv.sv = (ushort4){f2bf(hnew[0]), f2bf(hnew[1]), f2bf(hnew[2]), f2bf(hnew[3])};
    __hip_atomic_store(
        (unsigned long long*)(hping + (size_t)((t + 1) & 1) * HSLOT_SH +
                              (size_t)jgrp * 1024 + bg * 8 + 4 * kh),
        hv.u, __ATOMIC_RELAXED, __HIP_MEMORY_SCOPE_AGENT);

    // release: per-wave store ack, barrier (both waves), ONE arrival add
    asm volatile("s_waitcnt vmcnt(0)" ::: "memory");
    __syncthreads();
    if (tid == 0)
      __hip_atomic_fetch_add(finalc + (size_t)(t + 1) * 16, 1u,
                             __ATOMIC_RELAXED, __HIP_MEMORY_SCOPE_AGENT);

    // out stores AFTER the release — non-temporal
    f32x4 ov = {hnew[0], hnew[1], hnew[2], hnew[3]};
    __builtin_nontemporal_store(ov, (f32x4*)(out + ((size_t)bg * T_ + t) * H_ + jg));
    if (t == T_ - 1) {
      *(f32x4*)(hT + (size_t)bg * H_ + jg) = ov;
      f32x4 cv = {c_r[0], c_r[1], c_r[2], c_r[3]};
      *(f32x4*)(cT + (size_t)bg * H_ + jg) = cv;
    }

    // phase X for t+1 (cached loads), in the shadow of the wait
    if (t + 1 < T_) {
      #pragma unroll
      for (int q = 0; q < 16; ++q) {
        accs[0][q] = bias_r[q]; accs[1][q] = 0.f; accs[2][q] = 0.f; accs[3][q] = 0.f;
      }
      const unsigned short* xp =
          xTb + (size_t)(t + 1) * 98304 + (size_t)kh * 1024 + bg * 8;
      #pragma unroll
      for (int f = 0; f < 48; ++f) {
        short8v w = *(const short8v*)(wlb + wrow1 + (((2 * f + kh) ^ sw) << 4));
        short8v xv = *(const short8v*)(xp + f * 2048);
        accs[f & 3] = __builtin_amdgcn_mfma_f32_32x32x16_bf16(w, xv, accs[f & 3], 0, 0, 0);
      }
    }
  }
}

extern "C" void kernel_launch(void* const* d_in, const int* in_sizes, int n_in,
                              void* d_out, int out_size, void* d_ws, size_t ws_size,
                              hipStream_t stream) {
  const float* x   = (const float*)d_in[0];
  const float* h0  = (const float*)d_in[1];
  const float* c0  = (const float*)d_in[2];
  const float* wih = (const float*)d_in[3];
  const float* whh = (const float*)d_in[4];
  const float* bih = (const float*)d_in[5];
  const float* bhh = (const float*)d_in[6];

  float* out = (float*)d_out;
  float* hT  = out + (size_t)B_ * T_ * H_;
  float* cT  = hT + (size_t)B_ * H_;

  if (ws_size < WS_NEED) return;  // visible failure instead of OOB corruption

  char* ws = (char*)d_ws;
  unsigned*       finalc = (unsigned*)(ws);
  unsigned short* hping  = (unsigned short*)(ws + PING_OFF);
  float*          biasc  = (float*)(ws + BIAS_OFF);
  unsigned short* Wc     = (unsigned short*)(ws + WC_OFF);
  unsigned short* xTp    = (unsigned short*)(ws + XT_OFF);

  k_xT<<<dim3(T_), dim3(256), 0, stream>>>(x, xTp);
  k_prep_w<<<dim3(589824 / 256), dim3(256), 0, stream>>>(wih, whh, Wc);
  k_prep_s<<<dim3((B_ * H_) / 256), dim3(256), 0, stream>>>(h0, bih, bhh, hping, biasc, finalc);
  k_lstm<<<dim3(NWG), dim3(128), 0, stream>>>(xTp, Wc, biasc, c0, hping, finalc, out, hT, cT);
}